// Round 3
// baseline (83.141 us; speedup 1.0000x reference)
//
#include <hip/hip_runtime.h>

#define K      32
#define KQ     8                    // bins per lane (K split across lane QUADS)
#define TPB    256
#define NB     2048                 // 2048 blocks * 64 quad-slots * 16 = N
#define EPT    16                   // elements per quad-slot
#define NTOT   (32 * 64 * 1024)     // 2,097,152
#define PSTRIDE (NB * (TPB / 4))    // 131072 quad-slots per sweep

__device__ __forceinline__ float wave_reduce_sum(float v) {
#pragma unroll
  for (int m = 1; m < 64; m <<= 1) v += __shfl_xor(v, m, 64);
  return v;
}

// xor-1 neighbor add via DPP quad_perm(1,0,3,2): VALU-only, no LDS pipe.
__device__ __forceinline__ float dpp_xor1_add(float v) {
  int sw = __builtin_amdgcn_update_dpp(0, __builtin_bit_cast(int, v),
                                       0xB1, 0xF, 0xF, true);
  return v + __builtin_bit_cast(float, sw);
}
// xor-2 via quad_perm(2,3,0,1) = 0x4E
__device__ __forceinline__ float dpp_xor2_add(float v) {
  int sw = __builtin_amdgcn_update_dpp(0, __builtin_bit_cast(int, v),
                                       0x4E, 0xF, 0xF, true);
  return v + __builtin_bit_cast(float, sw);
}
// xor-8 via row_ror:8 (rotation by 8 within a 16-lane row == lane^8) = 0x128
__device__ __forceinline__ float dpp_xor8_add(float v) {
  int sw = __builtin_amdgcn_update_dpp(0, __builtin_bit_cast(int, v),
                                       0x128, 0xF, 0xF, true);
  return v + __builtin_bit_cast(float, sw);
}

// reduce across lanes of the SAME quad-position (16 lanes): masks 4,8,16,32.
// 8 is DPP row_ror (VALU); 4,16,32 stay shfl (no exact xor-DPP for them).
__device__ __forceinline__ float quad_lane_reduce(float v) {
  v += __shfl_xor(v, 4, 64);
  v = dpp_xor8_add(v);
  v += __shfl_xor(v, 16, 64);
  v += __shfl_xor(v, 32, 64);
  return v;
}

// Round-3 theory: R0-R2 showed total tracks the harness's 256MiB re-poison
// fill (~41us, inside the timed region) 1:1, and three structural rewrites
// of ssq_main moved nothing -> ssq_main is already near its ~10us issue
// floor. Remaining controllable budget is the tail: fuse ssq_reduce (33
// blocks) + ssq_final (1 wave) + their gap + the sums round-trip into ONE
// single-block 1024-thread kernel (partials are L2-hot, float4-vectorized).
// ssq_main math kept bit-identical; only branchless clamped prefetch added.
__global__ __launch_bounds__(TPB, 8)
void ssq_main(const float* __restrict__ x, const float* __restrict__ bins,
              float* __restrict__ out, float* __restrict__ partials) {
  const int tid   = threadIdx.x;
  const int quarter = tid & 3;                    // which 8-bin quarter
  const int qslot = blockIdx.x * (TPB / 4) + (tid >> 2);

  // this lane's 8 bins (VGPRs -- quarter-dependent, can't be SGPR)
  float binv[KQ];
#pragma unroll
  for (int j = 0; j < KQ; ++j) binv[j] = bins[KQ * quarter + j];
  float bs_local = 0.f;
#pragma unroll
  for (int j = 0; j < KQ; ++j) bs_local += binv[j];
  const float binsum = dpp_xor2_add(dpp_xor1_add(bs_local)); // all 32 bins
  const float epsb = 1e-10f * binsum;             // eps * sum(bins) term

  float sAcc[KQ];
#pragma unroll
  for (int j = 0; j < KQ; ++j) sAcc[j] = 0.f;
  float q = 0.f;

  const float Ch = -7.213475204444817f;           // 0.5 * ALPHA * log2(e)

  const float* xp = x + qslot;
  float xv_cur = xp[0];                           // 1-deep prefetch scalar

#pragma unroll 1
  for (int e = 0; e < EPT; ++e) {
    const float xv = xv_cur;
    const int en = (e + 1 < EPT) ? (e + 1) : (EPT - 1);   // branchless clamp
    xv_cur = xp[en * PSTRIDE];
    float t[KQ];                                  // static indices only
    float s0 = 0.f, s1 = 0.f, h0 = 0.f, h1 = 0.f, b0 = 0.f, b1 = 0.f;
#pragma unroll
    for (int j = 0; j < KQ; j += 2) {
      float ha = __builtin_amdgcn_exp2f(Ch * fabsf(xv - binv[j + 0]));
      float hb = __builtin_amdgcn_exp2f(Ch * fabsf(xv - binv[j + 1]));
      float ta = ha * ha, tb = hb * hb;
      t[j + 0] = ta; t[j + 1] = tb;
      s0 += ta; s1 += tb;
      h0 += ha; h1 += hb;
      b0 = fmaf(ta, binv[j + 0], b0);
      b1 = fmaf(tb, binv[j + 1], b1);
    }
    const float s_loc = s0 + s1;
    const float b_loc = b0 + b1;
    // combine the 4 lanes of the quad: xor1 then xor2, both pure-VALU DPP
    const float s_full = dpp_xor2_add(dpp_xor1_add(s_loc));
    const float b_full = dpp_xor2_add(dpp_xor1_add(b_loc));
    const float inv = __builtin_amdgcn_rcpf(s_full);
    // local hsum * rsqrt(s): summing q over ALL lanes later gives sum_k sqrt(a_k)
    q = fmaf(h0 + h1, __builtin_amdgcn_rsqf(s_full), q);
    if (quarter == 0) out[qslot + e * PSTRIDE] = fmaf(b_full, inv, epsb);
#pragma unroll
    for (int j = 0; j < KQ; ++j) sAcc[j] = fmaf(t[j], inv, sAcc[j]);
  }

  // block reduction. Same-quad-position reduce (masks 4,8,16,32): after it,
  // lanes 0..3 hold the bin sums for quarters 0..3 (lane==quarter there).
  __shared__ float red[4][K + 1];
  const int lane = tid & 63, wv = tid >> 6;
#pragma unroll
  for (int j = 0; j < KQ; ++j) {
    float v = quad_lane_reduce(sAcc[j]);
    if (lane < 4) red[wv][KQ * lane + j] = v;     // lane==quarter here
  }
  {
    float v = wave_reduce_sum(q);
    if (lane == 0) red[wv][K] = v;
  }
  __syncthreads();
  if (tid < K + 1) {
    float v = red[0][tid] + red[1][tid] + red[2][tid] + red[3][tid];
    partials[tid * NB + blockIdx.x] = v;          // written exactly once
  }
}

// ONE block, 1024 threads (16 waves): reduce all 33 partial rows (270 KB,
// L2-hot) + entropy + tails. Replaces ssq_reduce(33 blk) + gap + ssq_final.
// Wave w reduces rows w, w+16 (and wave 0 also row 32): 8 float4 loads/lane
// per row, wave-reduce, LDS. Then entropy over the 32 sums by wave 0.
__global__ __launch_bounds__(1024)
void ssq_tail(const float* __restrict__ partials, float* __restrict__ out) {
  const int tid  = threadIdx.x;
  const int wv   = tid >> 6, lane = tid & 63;
  __shared__ float sums[K + 1];

  for (int r = wv; r < K + 1; r += 16) {          // wave0: 0,16,32; wave1: 1,17; ...
    const float4* p = reinterpret_cast<const float4*>(partials + r * NB);
    float s = 0.f;
#pragma unroll
    for (int c = 0; c < NB / (64 * 4); ++c) {     // 8 x b128 per lane
      float4 v = p[c * 64 + lane];
      s += (v.x + v.y) + (v.z + v.w);
    }
    s = wave_reduce_sum(s);
    if (lane == 0) sums[r] = s;
  }
  __syncthreads();

  if (wv == 0) {                                  // wave 0 finishes
    float e = 0.f;
    if (lane < K) {
      float p = sums[lane] * (1.0f / (float)NTOT) + 1e-10f;  // eps folded in
      e = -p * __logf(p);
    }
    e = wave_reduce_sum(e);
    if (lane == 0) {
      out[NTOT + 0] = e;                              // code entropy
      out[NTOT + 1] = 0.f;                            // TAU
      out[NTOT + 2] = sums[K] * (1.0f / (float)NTOT); // quant loss
      out[NTOT + 3] = 0.f;                            // TAU2
    }
  }
}

extern "C" void kernel_launch(void* const* d_in, const int* in_sizes, int n_in,
                              void* d_out, int out_size, void* d_ws, size_t ws_size,
                              hipStream_t stream) {
  const float* x    = (const float*)d_in[0];
  const float* bins = (const float*)d_in[1];
  float* out        = (float*)d_out;
  float* partials   = (float*)d_ws;                 // (K+1)*NB floats = 264 KB

  ssq_main<<<NB, TPB,  0, stream>>>(x, bins, out, partials);
  ssq_tail<<<1,  1024, 0, stream>>>(partials, out);
}